// Round 8
// baseline (631.254 us; speedup 1.0000x reference)
//
#include <hip/hip_runtime.h>
#include <hip/hip_bf16.h>

#define DECAY_F 0.8f
#define OMD_F   0.2f
#define EPS_F   1e-5f

#define NROWS 16384
#define CBOOK 8192
#define DIM   256
#define KSPLIT 768   // [hi | lo | hi] x [hi | hi | lo]

// ---- ws layout (bytes) ----
#define WS_KEYS   0u
#define WS_ENORM  131072u
#define WS_COUNTS 163840u
#define WS_TOTAL  196608u
#define WS_XSPLIT 262144u
#define WS_ESPLIT_OFF (262144u + 25165824u)
#define WS_NEED   (WS_ESPLIT_OFF + 12582912u)

// ---- d_out layout (floats) ----
#define O_QUANT 0
#define O_IND   4194304
#define O_NORM  4210688
#define O_CSN   6307840
#define O_AVG   6316032

typedef __attribute__((ext_vector_type(8)))  short short8;
typedef __attribute__((ext_vector_type(4)))  float f32x4;
typedef __attribute__((ext_vector_type(4)))  unsigned short us4;

__device__ __forceinline__ unsigned int fkey(float f) {
    unsigned int b = __float_as_uint(f);
    return (b & 0x80000000u) ? ~b : (b | 0x80000000u);
}
__device__ __forceinline__ unsigned short f2bf(float f) {
    unsigned int u = __float_as_uint(f);
    unsigned int r = (u + 0x7FFFu + ((u >> 16) & 1u)) >> 16;
    return (unsigned short)r;
}
__device__ __forceinline__ float bf2f(unsigned short h) {
    return __uint_as_float(((unsigned int)h) << 16);
}

#define GLOAD_LDS16(g, l) \
    __builtin_amdgcn_global_load_lds((const __attribute__((address_space(1))) void*)(g), \
                                     (__attribute__((address_space(3))) void*)(l), 16, 0, 0)

// ---------- init embed_avg_new = 0.8*embed_avg ----------
__global__ __launch_bounds__(256) void init_avg_kernel(const float* __restrict__ embed_avg,
                                                       float* __restrict__ avg_out) {
    int i = blockIdx.x * 256 + threadIdx.x;
    float4 v = ((const float4*)embed_avg)[i];
    v.x *= DECAY_F; v.y *= DECAY_F; v.z *= DECAY_F; v.w *= DECAY_F;
    ((float4*)avg_out)[i] = v;
}

// ---------- x split: [hi, lo, hi] ----------
__global__ __launch_bounds__(256) void xsplit_kernel(const float* __restrict__ src,
                                                     unsigned short* __restrict__ dst) {
    int i = blockIdx.x * 256 + threadIdx.x;
    int e4  = i * 4;
    int row = e4 >> 8;
    int k   = e4 & 255;
    float4 v = ((const float4*)src)[i];
    us4 hi, lo;
    hi.x = f2bf(v.x); lo.x = f2bf(v.x - bf2f(hi.x));
    hi.y = f2bf(v.y); lo.y = f2bf(v.y - bf2f(hi.y));
    hi.z = f2bf(v.z); lo.z = f2bf(v.z - bf2f(hi.z));
    hi.w = f2bf(v.w); lo.w = f2bf(v.w - bf2f(hi.w));
    unsigned short* base = dst + (size_t)row * KSPLIT + k;
    *(us4*)(base + 0)   = hi;
    *(us4*)(base + 256) = lo;
    *(us4*)(base + 512) = hi;
}

// ---------- e split [hi, hi, lo] + fused ||e||^2 ----------
__global__ __launch_bounds__(256) void esplit_kernel(const float* __restrict__ embed,
                                                     unsigned short* __restrict__ dst,
                                                     float* __restrict__ enorm) {
    int row  = (blockIdx.x * 256 + threadIdx.x) >> 6;
    int lane = threadIdx.x & 63;
    float4 v = *(const float4*)&embed[row * DIM + lane * 4];
    float s = v.x * v.x + v.y * v.y + v.z * v.z + v.w * v.w;
    for (int m = 32; m >= 1; m >>= 1) s += __shfl_xor(s, m, 64);
    if (lane == 0) enorm[row] = s;
    us4 hi, lo;
    hi.x = f2bf(v.x); lo.x = f2bf(v.x - bf2f(hi.x));
    hi.y = f2bf(v.y); lo.y = f2bf(v.y - bf2f(hi.y));
    hi.z = f2bf(v.z); lo.z = f2bf(v.z - bf2f(hi.z));
    hi.w = f2bf(v.w); lo.w = f2bf(v.w - bf2f(hi.w));
    unsigned short* base = dst + (size_t)row * KSPLIT + lane * 4;
    *(us4*)(base + 0)   = hi;
    *(us4*)(base + 256) = hi;
    *(us4*)(base + 512) = lo;
}

// ============ 256x256 8-wave fine-phase MFMA GEMM (K=768) + fused argmin ============
// BK=32, 24 K-tiles, 3 LDS buffers (96 KB), depth-2 tile prefetch.
// Per tile: 2 phases, each {ds_read subtile ; 2 global_load_lds ; s_barrier ;
// lgkmcnt(0)+sched_barrier ; setprio1 ; 16 indep MFMA ; setprio0 ; [vmcnt cert] ; s_barrier}.
// Certify is COUNTED: vmcnt(4) leaves tile t+2's 4 loads in flight (T4, m218).
// Per-wave cert + barrier = global cert (all waves certify own loads pre-barrier).
// Swizzle: chunk ^ ((row>>1)&3) on 64B rows — parity-decorrelated (R6-proven),
// q-uniform (8 lanes per 4-bank group) on both ds_read and linear staging writes.
__global__ __launch_bounds__(512, 1) void mfma8_argmin_kernel(
        const unsigned short* __restrict__ A,
        const unsigned short* __restrict__ B,
        const float* __restrict__ enorm,
        unsigned long long* __restrict__ keys) {
    __shared__ __align__(16) unsigned short Al[3][8192];   // 256 rows x 32 k bf16 = 16 KB
    __shared__ __align__(16) unsigned short Bl[3][8192];

    const int tid  = threadIdx.x;
    const int lane = tid & 63;
    const int wid  = tid >> 6;      // 0..7
    const int wr   = wid >> 2;      // 0..1 -> 128-row half of A
    const int wc   = wid & 3;       // 0..3 -> 64-col quarter of B
    const int lr   = lane & 15;
    const int hk   = lane >> 4;     // 0..3

    // XCD-bijective swizzle; 2048 blocks (64 m x 32 n), 2048 % 8 == 0
    const int bid = blockIdx.x;
    const int swz = ((bid & 7) << 8) | (bid >> 3);
    const int bx  = swz & 31;
    const int by  = swz >> 5;
    const int mBase = by << 8;
    const int nBase = bx << 8;

    f32x4 acc[8][4];
#pragma unroll
    for (int m = 0; m < 8; m++)
#pragma unroll
        for (int n = 0; n < 4; n++) acc[m][n] = (f32x4)0.f;

    // ---- staging: per tile, A = 1024 slots of 16B (row=slot>>2, physchunk=slot&3),
    // 2 loads/thread; B same. Source pre-swizzled, LDS dest linear (rule #21).
    const unsigned short* gA[2]; int ldA[2];
    const unsigned short* gB[2]; int ldB[2];
#pragma unroll
    for (int l = 0; l < 2; l++) {
        int slot = l * 512 + tid;
        int row  = slot >> 2;
        int lg   = (slot & 3) ^ ((row >> 1) & 3);
        gA[l] = A + (size_t)(mBase + row) * KSPLIT + lg * 8;
        ldA[l] = slot * 8;
        gB[l] = B + (size_t)(nBase + row) * KSPLIT + lg * 8;
        ldB[l] = slot * 8;
    }

#define STAGE_A(bufn, t) do { \
    GLOAD_LDS16(gA[0] + (t) * 32, &Al[bufn][ldA[0]]); \
    GLOAD_LDS16(gA[1] + (t) * 32, &Al[bufn][ldA[1]]); \
} while (0)
#define STAGE_B(bufn, t) do { \
    GLOAD_LDS16(gB[0] + (t) * 32, &Bl[bufn][ldB[0]]); \
    GLOAD_LDS16(gB[1] + (t) * 32, &Bl[bufn][ldB[1]]); \
} while (0)

    // ---- read offsets: row R, logical chunk hk -> phys hk ^ ((R>>1)&3);
    // (R>>1)&3 == (lr>>1)&3 for all rows used (R = 16*f + lr forms).
    const int co = (hk ^ ((lr >> 1) & 3)) << 3;
    int aoff[8], boff[4];
#pragma unroll
    for (int m = 0; m < 8; m++) aoff[m] = (wr * 128 + m * 16 + lr) * 32 + co;
#pragma unroll
    for (int n = 0; n < 4; n++) boff[n] = (wc * 64 + n * 16 + lr) * 32 + co;

    // prologue: tiles 0,1 -> bufs 0,1; certify tile 0 (counted: tile1's 4 fly)
    STAGE_A(0, 0); STAGE_B(0, 0);
    STAGE_A(1, 1); STAGE_B(1, 1);
    asm volatile("s_waitcnt vmcnt(4)" ::: "memory");
    asm volatile("s_barrier" ::: "memory");

    int buf = 0, nbuf = 2;
    for (int t = 0; t < 24; ++t) {
        const unsigned short* ab = &Al[buf][0];
        const unsigned short* bb = &Bl[buf][0];
        short8 av[4], bv[4];

        // ---- phase 0: A-quad0 + all B; stage A(t+2)
#pragma unroll
        for (int m = 0; m < 4; m++) av[m] = *(const short8*)&ab[aoff[m]];
#pragma unroll
        for (int n = 0; n < 4; n++) bv[n] = *(const short8*)&bb[boff[n]];
        if (t < 22) STAGE_A(nbuf, t + 2);
        asm volatile("s_barrier" ::: "memory");
        asm volatile("s_waitcnt lgkmcnt(0)" ::: "memory");
        __builtin_amdgcn_sched_barrier(0);
        __builtin_amdgcn_s_setprio(1);
#pragma unroll
        for (int m = 0; m < 4; m++)
#pragma unroll
            for (int n = 0; n < 4; n++)
                acc[m][n] = __builtin_amdgcn_mfma_f32_16x16x32_bf16(av[m], bv[n], acc[m][n], 0, 0, 0);
        __builtin_amdgcn_s_setprio(0);
        asm volatile("s_barrier" ::: "memory");

        // ---- phase 1: A-quad1 (B held in regs); stage B(t+2); certify t+1
#pragma unroll
        for (int m = 0; m < 4; m++) av[m] = *(const short8*)&ab[aoff[4 + m]];
        if (t < 22) STAGE_B(nbuf, t + 2);
        asm volatile("s_barrier" ::: "memory");
        asm volatile("s_waitcnt lgkmcnt(0)" ::: "memory");
        __builtin_amdgcn_sched_barrier(0);
        __builtin_amdgcn_s_setprio(1);
#pragma unroll
        for (int m = 0; m < 4; m++)
#pragma unroll
            for (int n = 0; n < 4; n++)
                acc[4 + m][n] = __builtin_amdgcn_mfma_f32_16x16x32_bf16(av[m], bv[n], acc[4 + m][n], 0, 0, 0);
        __builtin_amdgcn_s_setprio(0);
        if (t < 22)      asm volatile("s_waitcnt vmcnt(4)" ::: "memory");
        else if (t < 23) asm volatile("s_waitcnt vmcnt(0)" ::: "memory");
        asm volatile("s_barrier" ::: "memory");

        int nb = buf + 1; if (nb == 3) nb = 0;      // buf = (t+1)%3
        int nn = nbuf + 1; if (nn == 3) nn = 0;     // nbuf = (t+3)%3
        buf = nb; nbuf = nn;
    }
#undef STAGE_A
#undef STAGE_B

    // ---- epilogue: score = ||e||^2 - 2*dot; argmin per row.
    // 16x16 C/D: col = lr, row-within-frag = hk*4 + reg  [m89/m91]
    float en[4];
    int   cc[4];
#pragma unroll
    for (int n = 0; n < 4; n++) {
        cc[n] = nBase + wc * 64 + n * 16 + lr;
        en[n] = enorm[cc[n]];
    }
#pragma unroll
    for (int m = 0; m < 8; m++) {
#pragma unroll
        for (int reg = 0; reg < 4; reg++) {
            float bs = 3.4e38f; int bc = 0;
#pragma unroll
            for (int n = 0; n < 4; n++) {
                float s = en[n] - 2.f * acc[m][n][reg];
                if (s < bs || (s == bs && cc[n] < bc)) { bs = s; bc = cc[n]; }
            }
            unsigned long long key =
                ((unsigned long long)fkey(bs) << 32) | (unsigned int)bc;
#pragma unroll
            for (int msk = 8; msk >= 1; msk >>= 1) {
                unsigned long long o = __shfl_xor(key, msk, 64);
                if (o < key) key = o;
            }
            if (lr == 0)
                atomicMin(&keys[mBase + wr * 128 + m * 16 + hk * 4 + reg], key);
        }
    }
}

// ---------- fallback fp32 fused GEMM+argmin ----------
#define BM 64
#define BN 256
#define KB 16
#define NSPLIT 4

__global__ __launch_bounds__(256) void argmin_kernel(const float* __restrict__ x,
                                                     const float* __restrict__ embed,
                                                     const float* __restrict__ enorm,
                                                     unsigned long long* __restrict__ keys) {
    __shared__ float xs[KB][BM];
    __shared__ float es[KB][BN];

    const int tid = threadIdx.x;
    const int tx = tid & 31;
    const int ty = tid >> 5;
    const int rowBase = blockIdx.x * BM;
    const int cStart = blockIdx.y * (CBOOK / NSPLIT);

    float bestS[8];
    int   bestC[8];
#pragma unroll
    for (int i = 0; i < 8; i++) { bestS[i] = 3.4e38f; bestC[i] = 0; }

    float acc[8][8];

    for (int cb = 0; cb < CBOOK / NSPLIT; cb += BN) {
        const int cbase = cStart + cb;
#pragma unroll
        for (int i = 0; i < 8; i++)
#pragma unroll
            for (int j = 0; j < 8; j++) acc[i][j] = 0.f;

        for (int kk = 0; kk < DIM; kk += KB) {
            __syncthreads();
            {
                int r  = tid >> 2;
                int k4 = (tid & 3) * 4;
                float4 v = *(const float4*)&x[(rowBase + r) * DIM + kk + k4];
                xs[k4 + 0][r] = v.x; xs[k4 + 1][r] = v.y;
                xs[k4 + 2][r] = v.z; xs[k4 + 3][r] = v.w;
            }
            {
                const float4* src = (const float4*)&embed[(cbase + tid) * DIM + kk];
#pragma unroll
                for (int q = 0; q < 4; q++) {
                    float4 v = src[q];
                    es[q * 4 + 0][tid] = v.x; es[q * 4 + 1][tid] = v.y;
                    es[q * 4 + 2][tid] = v.z; es[q * 4 + 3][tid] = v.w;
                }
            }
            __syncthreads();
#pragma unroll
            for (int k = 0; k < KB; k++) {
                float xr[8], er[8];
                *(float4*)&xr[0] = *(const float4*)&xs[k][ty * 8];
                *(float4*)&xr[4] = *(const float4*)&xs[k][ty * 8 + 4];
                *(float4*)&er[0] = *(const float4*)&es[k][tx * 4];
                *(float4*)&er[4] = *(const float4*)&es[k][128 + tx * 4];
#pragma unroll
                for (int i = 0; i < 8; i++)
#pragma unroll
                    for (int j = 0; j < 8; j++)
                        acc[i][j] = fmaf(xr[i], er[j], acc[i][j]);
            }
        }
#pragma unroll
        for (int j = 0; j < 8; j++) {
            int c = cbase + ((j < 4) ? (tx * 4 + j) : (128 + tx * 4 + (j - 4)));
            float en = enorm[c];
#pragma unroll
            for (int i = 0; i < 8; i++) {
                float s = en - 2.f * acc[i][j];
                if (s < bestS[i]) { bestS[i] = s; bestC[i] = c; }
            }
        }
    }

#pragma unroll
    for (int i = 0; i < 8; i++) {
        unsigned long long key =
            ((unsigned long long)fkey(bestS[i]) << 32) | (unsigned int)bestC[i];
        for (int m = 16; m >= 1; m >>= 1) {
            unsigned long long o = __shfl_xor(key, m, 64);
            if (o < key) key = o;
        }
        if (tx == 0) atomicMin(&keys[rowBase + ty * 8 + i], key);
    }
}

// ---------- scatter: quantize gather, ind write, counts, 0.2*x into avg ----------
__global__ __launch_bounds__(256) void scatter_kernel(const float* __restrict__ x,
                                                      const float* __restrict__ embed,
                                                      const unsigned long long* __restrict__ keys,
                                                      float* __restrict__ quant,
                                                      float* __restrict__ ind_out,
                                                      float* __restrict__ counts,
                                                      float* __restrict__ avg_out) {
    int i = blockIdx.x * 256 + threadIdx.x;
    int row = i >> 6;
    int c4  = (i & 63) * 4;
    int idx = (int)(keys[row] & 0xFFFFFFFFull);
    float4 e = *(const float4*)&embed[idx * DIM + c4];
    *(float4*)&quant[row * DIM + c4] = e;
    float4 xv = *(const float4*)&x[row * DIM + c4];
    atomicAdd(&avg_out[idx * DIM + c4 + 0], OMD_F * xv.x);
    atomicAdd(&avg_out[idx * DIM + c4 + 1], OMD_F * xv.y);
    atomicAdd(&avg_out[idx * DIM + c4 + 2], OMD_F * xv.z);
    atomicAdd(&avg_out[idx * DIM + c4 + 3], OMD_F * xv.w);
    if ((i & 63) == 0) {
        ind_out[row] = (float)idx;
        atomicAdd(&counts[idx], 1.0f);
    }
}

// ---------- cluster_size_new + total sum ----------
__global__ __launch_bounds__(256) void csn_kernel(const float* __restrict__ cluster_size,
                                                  const float* __restrict__ counts,
                                                  float* __restrict__ csn_out,
                                                  float* __restrict__ total) {
    int c = blockIdx.x * 256 + threadIdx.x;
    float v = DECAY_F * cluster_size[c] + OMD_F * counts[c];
    csn_out[c] = v;
    float s = v;
    for (int m = 32; m >= 1; m >>= 1) s += __shfl_xor(s, m, 64);
    __shared__ float ws4[4];
    if ((threadIdx.x & 63) == 0) ws4[threadIdx.x >> 6] = s;
    __syncthreads();
    if (threadIdx.x == 0) atomicAdd(total, ws4[0] + ws4[1] + ws4[2] + ws4[3]);
}

// ---------- embed_normalized = avg_new / cs ----------
__global__ __launch_bounds__(256) void norm_kernel(const float* __restrict__ avg_new,
                                                   const float* __restrict__ csn,
                                                   const float* __restrict__ total,
                                                   float* __restrict__ out) {
    int i = blockIdx.x * 256 + threadIdx.x;
    int c = i >> 6;
    float tot = *total;
    float smoothed = (csn[c] + EPS_F) / (tot + (float)CBOOK * EPS_F);
    float cs = smoothed * tot;
    float4 v = ((const float4*)avg_new)[i];
    v.x = v.x / cs; v.y = v.y / cs; v.z = v.z / cs; v.w = v.w / cs;
    ((float4*)out)[i] = v;
}

extern "C" void kernel_launch(void* const* d_in, const int* in_sizes, int n_in,
                              void* d_out, int out_size, void* d_ws, size_t ws_size,
                              hipStream_t stream) {
    const float* x            = (const float*)d_in[0];
    const float* embed        = (const float*)d_in[1];
    const float* cluster_size = (const float*)d_in[2];
    const float* embed_avg    = (const float*)d_in[3];
    float* out = (float*)d_out;
    char*  ws  = (char*)d_ws;

    unsigned long long* keys = (unsigned long long*)(ws + WS_KEYS);
    float* enorm  = (float*)(ws + WS_ENORM);
    float* counts = (float*)(ws + WS_COUNTS);
    float* total  = (float*)(ws + WS_TOTAL);

    hipMemsetAsync(ws + WS_KEYS, 0xFF, NROWS * 8, stream);
    hipMemsetAsync(ws + WS_COUNTS, 0, CBOOK * 4 + 4, stream);

    init_avg_kernel<<<(CBOOK * DIM / 4) / 256, 256, 0, stream>>>(embed_avg, out + O_AVG);

    if (ws_size >= (size_t)WS_NEED) {
        unsigned short* xsplit = (unsigned short*)(ws + WS_XSPLIT);
        unsigned short* esplit = (unsigned short*)(ws + WS_ESPLIT_OFF);
        xsplit_kernel<<<(NROWS * DIM / 4) / 256, 256, 0, stream>>>(x, xsplit);
        esplit_kernel<<<CBOOK / 4, 256, 0, stream>>>(embed, esplit, enorm);
        mfma8_argmin_kernel<<<(NROWS / 256) * (CBOOK / 256), 512, 0, stream>>>(
            xsplit, esplit, enorm, keys);
    } else {
        esplit_kernel<<<CBOOK / 4, 256, 0, stream>>>(embed, (unsigned short*)(ws + WS_XSPLIT), enorm);
        dim3 grid(NROWS / BM, NSPLIT);
        argmin_kernel<<<grid, 256, 0, stream>>>(x, embed, enorm, keys);
    }

    scatter_kernel<<<(NROWS * DIM / 4) / 256, 256, 0, stream>>>(
        x, embed, keys, out + O_QUANT, out + O_IND, counts, out + O_AVG);

    csn_kernel<<<CBOOK / 256, 256, 0, stream>>>(cluster_size, counts, out + O_CSN, total);

    norm_kernel<<<(CBOOK * DIM / 4) / 256, 256, 0, stream>>>(
        out + O_AVG, out + O_CSN, total, out + O_NORM);
}

// Round 9
// 445.709 us; speedup vs baseline: 1.4163x; 1.4163x over previous
//
#include <hip/hip_runtime.h>
#include <hip/hip_bf16.h>

#define DECAY_F 0.8f
#define OMD_F   0.2f
#define EPS_F   1e-5f

#define NROWS 16384
#define CBOOK 8192
#define DIM   256
#define KSPLIT 768   // [hi | lo | hi] x [hi | hi | lo]

// ---- ws layout (bytes) ----
#define WS_KEYS   0u
#define WS_ENORM  131072u
#define WS_COUNTS 163840u
#define WS_TOTAL  196608u
#define WS_XSPLIT 262144u
#define WS_ESPLIT_OFF (262144u + 25165824u)
#define WS_NEED   (WS_ESPLIT_OFF + 12582912u)

// ---- d_out layout (floats) ----
#define O_QUANT 0
#define O_IND   4194304
#define O_NORM  4210688
#define O_CSN   6307840
#define O_AVG   6316032

typedef __attribute__((ext_vector_type(8))) short short8;
typedef __attribute__((ext_vector_type(4))) float f32x4;
typedef __attribute__((ext_vector_type(4))) unsigned short us4;

__device__ __forceinline__ unsigned int fkey(float f) {
    unsigned int b = __float_as_uint(f);
    return (b & 0x80000000u) ? ~b : (b | 0x80000000u);
}
__device__ __forceinline__ unsigned short f2bf(float f) {
    unsigned int u = __float_as_uint(f);
    unsigned int r = (u + 0x7FFFu + ((u >> 16) & 1u)) >> 16;
    return (unsigned short)r;
}
__device__ __forceinline__ float bf2f(unsigned short h) {
    return __uint_as_float(((unsigned int)h) << 16);
}

#define GLOAD_LDS16(g, l) \
    __builtin_amdgcn_global_load_lds((const __attribute__((address_space(1))) void*)(g), \
                                     (__attribute__((address_space(3))) void*)(l), 16, 0, 0)

// ---------- init embed_avg_new = 0.8*embed_avg ----------
__global__ __launch_bounds__(256) void init_avg_kernel(const float* __restrict__ embed_avg,
                                                       float* __restrict__ avg_out) {
    int i = blockIdx.x * 256 + threadIdx.x;
    float4 v = ((const float4*)embed_avg)[i];
    v.x *= DECAY_F; v.y *= DECAY_F; v.z *= DECAY_F; v.w *= DECAY_F;
    ((float4*)avg_out)[i] = v;
}

// ---------- x split: [hi, lo, hi] ----------
__global__ __launch_bounds__(256) void xsplit_kernel(const float* __restrict__ src,
                                                     unsigned short* __restrict__ dst) {
    int i = blockIdx.x * 256 + threadIdx.x;
    int e4  = i * 4;
    int row = e4 >> 8;
    int k   = e4 & 255;
    float4 v = ((const float4*)src)[i];
    us4 hi, lo;
    hi.x = f2bf(v.x); lo.x = f2bf(v.x - bf2f(hi.x));
    hi.y = f2bf(v.y); lo.y = f2bf(v.y - bf2f(hi.y));
    hi.z = f2bf(v.z); lo.z = f2bf(v.z - bf2f(hi.z));
    hi.w = f2bf(v.w); lo.w = f2bf(v.w - bf2f(hi.w));
    unsigned short* base = dst + (size_t)row * KSPLIT + k;
    *(us4*)(base + 0)   = hi;
    *(us4*)(base + 256) = lo;
    *(us4*)(base + 512) = hi;
}

// ---------- e split [hi, hi, lo] + fused ||e||^2 ----------
__global__ __launch_bounds__(256) void esplit_kernel(const float* __restrict__ embed,
                                                     unsigned short* __restrict__ dst,
                                                     float* __restrict__ enorm) {
    int row  = (blockIdx.x * 256 + threadIdx.x) >> 6;
    int lane = threadIdx.x & 63;
    float4 v = *(const float4*)&embed[row * DIM + lane * 4];
    float s = v.x * v.x + v.y * v.y + v.z * v.z + v.w * v.w;
    for (int m = 32; m >= 1; m >>= 1) s += __shfl_xor(s, m, 64);
    if (lane == 0) enorm[row] = s;
    us4 hi, lo;
    hi.x = f2bf(v.x); lo.x = f2bf(v.x - bf2f(hi.x));
    hi.y = f2bf(v.y); lo.y = f2bf(v.y - bf2f(hi.y));
    hi.z = f2bf(v.z); lo.z = f2bf(v.z - bf2f(hi.z));
    hi.w = f2bf(v.w); lo.w = f2bf(v.w - bf2f(hi.w));
    unsigned short* base = dst + (size_t)row * KSPLIT + lane * 4;
    *(us4*)(base + 0)   = hi;
    *(us4*)(base + 256) = hi;
    *(us4*)(base + 512) = lo;
}

// ============ 128x128 MFMA GEMM (K=768) + fused per-row argmin ============
// R3 geometry EXACTLY (4 waves 2x2, 16x16x32, proven swizzle, 96% L2 hit) +
// counted-vmcnt pipeline (T4): 3 LDS buffers, depth-2 tile prefetch, ONE raw
// s_barrier per K-tile, vmcnt(4) certify (tile t+1's 4 loads stay in flight).
// Hazards: lgkm(0) pre-MFMA drains each wave's reads before it reaches the
// next barrier -> staging t+2 into buf (t-1)%3 after that barrier is WAR-safe;
// per-wave vmcnt(4) + barrier = global RAW certify of tile t.
__global__ __launch_bounds__(256, 3) void mfma_argmin_kernel(
        const unsigned short* __restrict__ A,
        const unsigned short* __restrict__ B,
        const float* __restrict__ enorm,
        unsigned long long* __restrict__ keys) {
    __shared__ __align__(16) unsigned short Al[3][128 * 32];   // 3 x 8 KB
    __shared__ __align__(16) unsigned short Bl[3][128 * 32];   // 3 x 8 KB

    const int tid  = threadIdx.x;
    const int lane = tid & 63;
    const int wid  = tid >> 6;
    const int wr = wid >> 1, wc = wid & 1;
    const int mBase = blockIdx.y * 128;
    const int nBase = blockIdx.x * 128;

    const int lr = lane & 15;
    const int hk = lane >> 4;

    f32x4 acc[4][4];
#pragma unroll
    for (int i = 0; i < 4; i++)
#pragma unroll
        for (int n = 0; n < 4; n++) acc[i][n] = (f32x4)0.f;

    // staging: LDS dest linear (tid*16B); global source chunk pre-swizzled
    // phys chunk p = tid&3 holds logical chunk p ^ ((r>>1)&3)  (R3-proven).
    const int r0 = tid >> 2;
    const int ck = (((tid & 3) ^ ((r0 >> 1) & 3)) << 3);
    const unsigned short* gA0 = A + (size_t)(mBase + r0) * KSPLIT + ck;
    const unsigned short* gA1 = gA0 + (size_t)64 * KSPLIT;
    const unsigned short* gB0 = B + (size_t)(nBase + r0) * KSPLIT + ck;
    const unsigned short* gB1 = gB0 + (size_t)64 * KSPLIT;

#define STAGE(b, kk) do { \
    GLOAD_LDS16(gA0 + (kk), &Al[b][tid * 8]); \
    GLOAD_LDS16(gA1 + (kk), &Al[b][(tid + 256) * 8]); \
    GLOAD_LDS16(gB0 + (kk), &Bl[b][tid * 8]); \
    GLOAD_LDS16(gB1 + (kk), &Bl[b][(tid + 256) * 8]); \
} while (0)

    // read offsets (same swizzle on read side)
    const int co = ((hk ^ ((lr >> 1) & 3)) << 3);
    int aoff[4], boff[4];
#pragma unroll
    for (int i = 0; i < 4; i++) {
        aoff[i] = (wr * 64 + i * 16 + lr) * 32 + co;
        boff[i] = (wc * 64 + i * 16 + lr) * 32 + co;
    }

    // prologue: stage tiles 0,1 (8 loads/wave outstanding)
    STAGE(0, 0);
    STAGE(1, 32);

#pragma unroll 3
    for (int t = 0; t < 24; ++t) {
        if (t < 23) asm volatile("s_waitcnt vmcnt(4)" ::: "memory");  // tile t certified
        else        asm volatile("s_waitcnt vmcnt(0)" ::: "memory");
        asm volatile("s_barrier" ::: "memory");
        if (t < 22) STAGE((t + 2) % 3, (t + 2) * 32);   // depth-2 prefetch

        const int b = t % 3;
        short8 af[4], bf4[4];
#pragma unroll
        for (int i = 0; i < 4; i++) af[i]  = *(const short8*)&Al[b][aoff[i]];
#pragma unroll
        for (int n = 0; n < 4; n++) bf4[n] = *(const short8*)&Bl[b][boff[n]];
        asm volatile("s_waitcnt lgkmcnt(0)" ::: "memory");
        __builtin_amdgcn_sched_barrier(0);
        __builtin_amdgcn_s_setprio(1);
#pragma unroll
        for (int i = 0; i < 4; i++)
#pragma unroll
            for (int n = 0; n < 4; n++)
                acc[i][n] = __builtin_amdgcn_mfma_f32_16x16x32_bf16(af[i], bf4[n], acc[i][n], 0, 0, 0);
        __builtin_amdgcn_s_setprio(0);
    }
#undef STAGE

    // epilogue: score = ||e||^2 - 2*dot; per-row argmin (R3-identical)
    float en4[4];
    int   c4[4];
#pragma unroll
    for (int n = 0; n < 4; n++) {
        c4[n]  = nBase + wc * 64 + n * 16 + lr;
        en4[n] = enorm[c4[n]];
    }
#pragma unroll
    for (int i = 0; i < 4; i++) {
#pragma unroll
        for (int reg = 0; reg < 4; reg++) {
            float bs = 3.4e38f; int bc = 0;
#pragma unroll
            for (int n = 0; n < 4; n++) {
                float s = en4[n] - 2.f * acc[i][n][reg];
                if (s < bs || (s == bs && c4[n] < bc)) { bs = s; bc = c4[n]; }
            }
            unsigned long long key =
                ((unsigned long long)fkey(bs) << 32) | (unsigned int)bc;
#pragma unroll
            for (int m = 8; m >= 1; m >>= 1) {
                unsigned long long o = __shfl_xor(key, m, 64);
                if (o < key) key = o;
            }
            if (lr == 0)
                atomicMin(&keys[mBase + wr * 64 + i * 16 + hk * 4 + reg], key);
        }
    }
}

// ---------- fallback fp32 fused GEMM+argmin ----------
#define BM 64
#define BN 256
#define KB 16
#define NSPLIT 4

__global__ __launch_bounds__(256) void argmin_kernel(const float* __restrict__ x,
                                                     const float* __restrict__ embed,
                                                     const float* __restrict__ enorm,
                                                     unsigned long long* __restrict__ keys) {
    __shared__ float xs[KB][BM];
    __shared__ float es[KB][BN];

    const int tid = threadIdx.x;
    const int tx = tid & 31;
    const int ty = tid >> 5;
    const int rowBase = blockIdx.x * BM;
    const int cStart = blockIdx.y * (CBOOK / NSPLIT);

    float bestS[8];
    int   bestC[8];
#pragma unroll
    for (int i = 0; i < 8; i++) { bestS[i] = 3.4e38f; bestC[i] = 0; }

    float acc[8][8];

    for (int cb = 0; cb < CBOOK / NSPLIT; cb += BN) {
        const int cbase = cStart + cb;
#pragma unroll
        for (int i = 0; i < 8; i++)
#pragma unroll
            for (int j = 0; j < 8; j++) acc[i][j] = 0.f;

        for (int kk = 0; kk < DIM; kk += KB) {
            __syncthreads();
            {
                int r  = tid >> 2;
                int k4 = (tid & 3) * 4;
                float4 v = *(const float4*)&x[(rowBase + r) * DIM + kk + k4];
                xs[k4 + 0][r] = v.x; xs[k4 + 1][r] = v.y;
                xs[k4 + 2][r] = v.z; xs[k4 + 3][r] = v.w;
            }
            {
                const float4* src = (const float4*)&embed[(cbase + tid) * DIM + kk];
#pragma unroll
                for (int q = 0; q < 4; q++) {
                    float4 v = src[q];
                    es[q * 4 + 0][tid] = v.x; es[q * 4 + 1][tid] = v.y;
                    es[q * 4 + 2][tid] = v.z; es[q * 4 + 3][tid] = v.w;
                }
            }
            __syncthreads();
#pragma unroll
            for (int k = 0; k < KB; k++) {
                float xr[8], er[8];
                *(float4*)&xr[0] = *(const float4*)&xs[k][ty * 8];
                *(float4*)&xr[4] = *(const float4*)&xs[k][ty * 8 + 4];
                *(float4*)&er[0] = *(const float4*)&es[k][tx * 4];
                *(float4*)&er[4] = *(const float4*)&es[k][128 + tx * 4];
#pragma unroll
                for (int i = 0; i < 8; i++)
#pragma unroll
                    for (int j = 0; j < 8; j++)
                        acc[i][j] = fmaf(xr[i], er[j], acc[i][j]);
            }
        }
#pragma unroll
        for (int j = 0; j < 8; j++) {
            int c = cbase + ((j < 4) ? (tx * 4 + j) : (128 + tx * 4 + (j - 4)));
            float en = enorm[c];
#pragma unroll
            for (int i = 0; i < 8; i++) {
                float s = en - 2.f * acc[i][j];
                if (s < bestS[i]) { bestS[i] = s; bestC[i] = c; }
            }
        }
    }

#pragma unroll
    for (int i = 0; i < 8; i++) {
        unsigned long long key =
            ((unsigned long long)fkey(bestS[i]) << 32) | (unsigned int)bestC[i];
        for (int m = 16; m >= 1; m >>= 1) {
            unsigned long long o = __shfl_xor(key, m, 64);
            if (o < key) key = o;
        }
        if (tx == 0) atomicMin(&keys[rowBase + ty * 8 + i], key);
    }
}

// ---------- scatter: quantize gather, ind write, counts, 0.2*x into avg ----------
__global__ __launch_bounds__(256) void scatter_kernel(const float* __restrict__ x,
                                                      const float* __restrict__ embed,
                                                      const unsigned long long* __restrict__ keys,
                                                      float* __restrict__ quant,
                                                      float* __restrict__ ind_out,
                                                      float* __restrict__ counts,
                                                      float* __restrict__ avg_out) {
    int i = blockIdx.x * 256 + threadIdx.x;
    int row = i >> 6;
    int c4  = (i & 63) * 4;
    int idx = (int)(keys[row] & 0xFFFFFFFFull);
    float4 e = *(const float4*)&embed[idx * DIM + c4];
    *(float4*)&quant[row * DIM + c4] = e;
    float4 xv = *(const float4*)&x[row * DIM + c4];
    atomicAdd(&avg_out[idx * DIM + c4 + 0], OMD_F * xv.x);
    atomicAdd(&avg_out[idx * DIM + c4 + 1], OMD_F * xv.y);
    atomicAdd(&avg_out[idx * DIM + c4 + 2], OMD_F * xv.z);
    atomicAdd(&avg_out[idx * DIM + c4 + 3], OMD_F * xv.w);
    if ((i & 63) == 0) {
        ind_out[row] = (float)idx;
        atomicAdd(&counts[idx], 1.0f);
    }
}

// ---------- cluster_size_new + total sum ----------
__global__ __launch_bounds__(256) void csn_kernel(const float* __restrict__ cluster_size,
                                                  const float* __restrict__ counts,
                                                  float* __restrict__ csn_out,
                                                  float* __restrict__ total) {
    int c = blockIdx.x * 256 + threadIdx.x;
    float v = DECAY_F * cluster_size[c] + OMD_F * counts[c];
    csn_out[c] = v;
    float s = v;
    for (int m = 32; m >= 1; m >>= 1) s += __shfl_xor(s, m, 64);
    __shared__ float ws4[4];
    if ((threadIdx.x & 63) == 0) ws4[threadIdx.x >> 6] = s;
    __syncthreads();
    if (threadIdx.x == 0) atomicAdd(total, ws4[0] + ws4[1] + ws4[2] + ws4[3]);
}

// ---------- embed_normalized = avg_new / cs ----------
__global__ __launch_bounds__(256) void norm_kernel(const float* __restrict__ avg_new,
                                                   const float* __restrict__ csn,
                                                   const float* __restrict__ total,
                                                   float* __restrict__ out) {
    int i = blockIdx.x * 256 + threadIdx.x;
    int c = i >> 6;
    float tot = *total;
    float smoothed = (csn[c] + EPS_F) / (tot + (float)CBOOK * EPS_F);
    float cs = smoothed * tot;
    float4 v = ((const float4*)avg_new)[i];
    v.x = v.x / cs; v.y = v.y / cs; v.z = v.z / cs; v.w = v.w / cs;
    ((float4*)out)[i] = v;
}

extern "C" void kernel_launch(void* const* d_in, const int* in_sizes, int n_in,
                              void* d_out, int out_size, void* d_ws, size_t ws_size,
                              hipStream_t stream) {
    const float* x            = (const float*)d_in[0];
    const float* embed        = (const float*)d_in[1];
    const float* cluster_size = (const float*)d_in[2];
    const float* embed_avg    = (const float*)d_in[3];
    float* out = (float*)d_out;
    char*  ws  = (char*)d_ws;

    unsigned long long* keys = (unsigned long long*)(ws + WS_KEYS);
    float* enorm  = (float*)(ws + WS_ENORM);
    float* counts = (float*)(ws + WS_COUNTS);
    float* total  = (float*)(ws + WS_TOTAL);

    hipMemsetAsync(ws + WS_KEYS, 0xFF, NROWS * 8, stream);
    hipMemsetAsync(ws + WS_COUNTS, 0, CBOOK * 4 + 4, stream);

    init_avg_kernel<<<(CBOOK * DIM / 4) / 256, 256, 0, stream>>>(embed_avg, out + O_AVG);

    if (ws_size >= (size_t)WS_NEED) {
        unsigned short* xsplit = (unsigned short*)(ws + WS_XSPLIT);
        unsigned short* esplit = (unsigned short*)(ws + WS_ESPLIT_OFF);
        xsplit_kernel<<<(NROWS * DIM / 4) / 256, 256, 0, stream>>>(x, xsplit);
        esplit_kernel<<<CBOOK / 4, 256, 0, stream>>>(embed, esplit, enorm);
        dim3 grid(CBOOK / 128, NROWS / 128);
        mfma_argmin_kernel<<<grid, 256, 0, stream>>>(xsplit, esplit, enorm, keys);
    } else {
        esplit_kernel<<<CBOOK / 4, 256, 0, stream>>>(embed, (unsigned short*)(ws + WS_XSPLIT), enorm);
        dim3 grid(NROWS / BM, NSPLIT);
        argmin_kernel<<<grid, 256, 0, stream>>>(x, embed, enorm, keys);
    }

    scatter_kernel<<<(NROWS * DIM / 4) / 256, 256, 0, stream>>>(
        x, embed, keys, out + O_QUANT, out + O_IND, counts, out + O_AVG);

    csn_kernel<<<CBOOK / 256, 256, 0, stream>>>(cluster_size, counts, out + O_CSN, total);

    norm_kernel<<<(CBOOK * DIM / 4) / 256, 256, 0, stream>>>(
        out + O_AVG, out + O_CSN, total, out + O_NORM);
}

// Round 10
// 412.061 us; speedup vs baseline: 1.5319x; 1.0817x over previous
//
#include <hip/hip_runtime.h>
#include <hip/hip_bf16.h>

#define DECAY_F 0.8f
#define OMD_F   0.2f
#define EPS_F   1e-5f

#define NROWS 16384
#define CBOOK 8192
#define DIM   256
#define KSPLIT 768   // [hi | lo | hi] x [hi | hi | lo]

// ---- ws layout (bytes) ----
#define WS_KEYS   0u
#define WS_ENORM  131072u
#define WS_COUNTS 163840u
#define WS_TOTAL  196608u
#define WS_XSPLIT 262144u
#define WS_ESPLIT_OFF (262144u + 25165824u)
#define WS_NEED   (WS_ESPLIT_OFF + 12582912u)

// ---- d_out layout (floats) ----
#define O_QUANT 0
#define O_IND   4194304
#define O_NORM  4210688
#define O_CSN   6307840
#define O_AVG   6316032

typedef __attribute__((ext_vector_type(8))) short short8;
typedef __attribute__((ext_vector_type(4))) float f32x4;
typedef __attribute__((ext_vector_type(4))) unsigned short us4;

__device__ __forceinline__ unsigned int fkey(float f) {
    unsigned int b = __float_as_uint(f);
    return (b & 0x80000000u) ? ~b : (b | 0x80000000u);
}
__device__ __forceinline__ unsigned short f2bf(float f) {
    unsigned int u = __float_as_uint(f);
    unsigned int r = (u + 0x7FFFu + ((u >> 16) & 1u)) >> 16;
    return (unsigned short)r;
}
__device__ __forceinline__ float bf2f(unsigned short h) {
    return __uint_as_float(((unsigned int)h) << 16);
}

#define GLOAD_LDS16(g, l) \
    __builtin_amdgcn_global_load_lds((const __attribute__((address_space(1))) void*)(g), \
                                     (__attribute__((address_space(3))) void*)(l), 16, 0, 0)

// ---------- fused prep: xsplit | (esplit + enorm + init_avg) ----------
// blocks [0,4096): xsplit [hi,lo,hi]  (one float4 per thread)
// blocks [4096,6144): 4 e-rows per block (1 wave/row): esplit [hi,hi,lo],
//                     enorm, and avg_out = 0.8*embed_avg for the same rows.
__global__ __launch_bounds__(256) void prep_kernel(const float* __restrict__ x,
                                                   const float* __restrict__ embed,
                                                   const float* __restrict__ embed_avg,
                                                   unsigned short* __restrict__ xsplit,
                                                   unsigned short* __restrict__ esplit,
                                                   float* __restrict__ enorm,
                                                   float* __restrict__ avg_out) {
    const int b = blockIdx.x;
    if (b < 4096) {
        int i = b * 256 + threadIdx.x;      // float4 index
        int e4  = i * 4;
        int row = e4 >> 8;
        int k   = e4 & 255;
        float4 v = ((const float4*)x)[i];
        us4 hi, lo;
        hi.x = f2bf(v.x); lo.x = f2bf(v.x - bf2f(hi.x));
        hi.y = f2bf(v.y); lo.y = f2bf(v.y - bf2f(hi.y));
        hi.z = f2bf(v.z); lo.z = f2bf(v.z - bf2f(hi.z));
        hi.w = f2bf(v.w); lo.w = f2bf(v.w - bf2f(hi.w));
        unsigned short* base = xsplit + (size_t)row * KSPLIT + k;
        *(us4*)(base + 0)   = hi;
        *(us4*)(base + 256) = lo;
        *(us4*)(base + 512) = hi;
    } else {
        int bb   = b - 4096;
        int row  = bb * 4 + (threadIdx.x >> 6);
        int lane = threadIdx.x & 63;
        float4 v = *(const float4*)&embed[row * DIM + lane * 4];
        float s = v.x * v.x + v.y * v.y + v.z * v.z + v.w * v.w;
        for (int m = 32; m >= 1; m >>= 1) s += __shfl_xor(s, m, 64);
        if (lane == 0) enorm[row] = s;
        us4 hi, lo;
        hi.x = f2bf(v.x); lo.x = f2bf(v.x - bf2f(hi.x));
        hi.y = f2bf(v.y); lo.y = f2bf(v.y - bf2f(hi.y));
        hi.z = f2bf(v.z); lo.z = f2bf(v.z - bf2f(hi.z));
        hi.w = f2bf(v.w); lo.w = f2bf(v.w - bf2f(hi.w));
        unsigned short* base = esplit + (size_t)row * KSPLIT + lane * 4;
        *(us4*)(base + 0)   = hi;
        *(us4*)(base + 256) = hi;
        *(us4*)(base + 512) = lo;
        // init avg_out for the same e-rows
        float4 av = *(const float4*)&embed_avg[row * DIM + lane * 4];
        av.x *= DECAY_F; av.y *= DECAY_F; av.z *= DECAY_F; av.w *= DECAY_F;
        *(float4*)&avg_out[row * DIM + lane * 4] = av;
    }
}

// ---------- standalone enorm (fallback path only) ----------
__global__ __launch_bounds__(256) void enorm_kernel(const float* __restrict__ embed,
                                                    float* __restrict__ enorm) {
    int row  = (blockIdx.x * 256 + threadIdx.x) >> 6;
    int lane = threadIdx.x & 63;
    float4 v = *(const float4*)&embed[row * DIM + lane * 4];
    float s = v.x * v.x + v.y * v.y + v.z * v.z + v.w * v.w;
    for (int m = 32; m >= 1; m >>= 1) s += __shfl_xor(s, m, 64);
    if (lane == 0) enorm[row] = s;
}

// ---------- init embed_avg_new = 0.8*embed_avg (fallback path only) ----------
__global__ __launch_bounds__(256) void init_avg_kernel(const float* __restrict__ embed_avg,
                                                       float* __restrict__ avg_out) {
    int i = blockIdx.x * 256 + threadIdx.x;
    float4 v = ((const float4*)embed_avg)[i];
    v.x *= DECAY_F; v.y *= DECAY_F; v.z *= DECAY_F; v.w *= DECAY_F;
    ((float4*)avg_out)[i] = v;
}

// ============ R3-proven 128x128 MFMA GEMM (K=768) + fused argmin ============
// 4 waves 2x2, 16x16x32, 2 LDS buffers, __syncthreads pipeline (m114: co-resident
// blocks hide the drain), proven parity-decorrelated swizzle (0 conflicts).
// Only change vs R3: __launch_bounds__(256,5) -> 5 blocks/CU (5 x 32KB = 160KB).
__global__ __launch_bounds__(256, 5) void mfma_argmin_kernel(
        const unsigned short* __restrict__ A,
        const unsigned short* __restrict__ B,
        const float* __restrict__ enorm,
        unsigned long long* __restrict__ keys) {
    __shared__ __align__(16) unsigned short Al[2][128 * 32];
    __shared__ __align__(16) unsigned short Bl[2][128 * 32];

    const int tid  = threadIdx.x;
    const int lane = tid & 63;
    const int wid  = tid >> 6;
    const int wr = wid >> 1, wc = wid & 1;
    const int mBase = blockIdx.y * 128;
    const int nBase = blockIdx.x * 128;

    const int lr = lane & 15;
    const int hk = lane >> 4;

    f32x4 acc[4][4];
#pragma unroll
    for (int i = 0; i < 4; i++)
#pragma unroll
        for (int n = 0; n < 4; n++) acc[i][n] = (f32x4)0.f;

    const int r0 = tid >> 2;
    const int ck = (((tid & 3) ^ ((r0 >> 1) & 3)) << 3);
    const unsigned short* gA0 = A + (size_t)(mBase + r0) * KSPLIT + ck;
    const unsigned short* gA1 = gA0 + (size_t)64 * KSPLIT;
    const unsigned short* gB0 = B + (size_t)(nBase + r0) * KSPLIT + ck;
    const unsigned short* gB1 = gB0 + (size_t)64 * KSPLIT;

#define STAGE(b, kk) do { \
    GLOAD_LDS16(gA0 + (kk), &Al[b][tid * 8]); \
    GLOAD_LDS16(gA1 + (kk), &Al[b][(tid + 256) * 8]); \
    GLOAD_LDS16(gB0 + (kk), &Bl[b][tid * 8]); \
    GLOAD_LDS16(gB1 + (kk), &Bl[b][(tid + 256) * 8]); \
} while (0)

    const int co = ((hk ^ ((lr >> 1) & 3)) << 3);
    int aoff[4], boff[4];
#pragma unroll
    for (int i = 0; i < 4; i++) {
        aoff[i] = (wr * 64 + i * 16 + lr) * 32 + co;
        boff[i] = (wc * 64 + i * 16 + lr) * 32 + co;
    }

    STAGE(0, 0);
    __syncthreads();

#pragma unroll 2
    for (int t = 0; t < 24; ++t) {
        const int cur = t & 1;
        if (t < 23) STAGE(cur ^ 1, (t + 1) * 32);

        short8 af[4], bf4[4];
#pragma unroll
        for (int i = 0; i < 4; i++) af[i]  = *(const short8*)&Al[cur][aoff[i]];
#pragma unroll
        for (int n = 0; n < 4; n++) bf4[n] = *(const short8*)&Bl[cur][boff[n]];
#pragma unroll
        for (int i = 0; i < 4; i++)
#pragma unroll
            for (int n = 0; n < 4; n++)
                acc[i][n] = __builtin_amdgcn_mfma_f32_16x16x32_bf16(af[i], bf4[n], acc[i][n], 0, 0, 0);

        __syncthreads();
    }
#undef STAGE

    float en4[4];
    int   c4[4];
#pragma unroll
    for (int n = 0; n < 4; n++) {
        c4[n]  = nBase + wc * 64 + n * 16 + lr;
        en4[n] = enorm[c4[n]];
    }
#pragma unroll
    for (int i = 0; i < 4; i++) {
#pragma unroll
        for (int reg = 0; reg < 4; reg++) {
            float bs = 3.4e38f; int bc = 0;
#pragma unroll
            for (int n = 0; n < 4; n++) {
                float s = en4[n] - 2.f * acc[i][n][reg];
                if (s < bs || (s == bs && c4[n] < bc)) { bs = s; bc = c4[n]; }
            }
            unsigned long long key =
                ((unsigned long long)fkey(bs) << 32) | (unsigned int)bc;
#pragma unroll
            for (int m = 8; m >= 1; m >>= 1) {
                unsigned long long o = __shfl_xor(key, m, 64);
                if (o < key) key = o;
            }
            if (lr == 0)
                atomicMin(&keys[mBase + wr * 64 + i * 16 + hk * 4 + reg], key);
        }
    }
}

// ---------- fallback fp32 fused GEMM+argmin ----------
#define BM 64
#define BN 256
#define KB 16
#define NSPLIT 4

__global__ __launch_bounds__(256) void argmin_kernel(const float* __restrict__ x,
                                                     const float* __restrict__ embed,
                                                     const float* __restrict__ enorm,
                                                     unsigned long long* __restrict__ keys) {
    __shared__ float xs[KB][BM];
    __shared__ float es[KB][BN];

    const int tid = threadIdx.x;
    const int tx = tid & 31;
    const int ty = tid >> 5;
    const int rowBase = blockIdx.x * BM;
    const int cStart = blockIdx.y * (CBOOK / NSPLIT);

    float bestS[8];
    int   bestC[8];
#pragma unroll
    for (int i = 0; i < 8; i++) { bestS[i] = 3.4e38f; bestC[i] = 0; }

    float acc[8][8];

    for (int cb = 0; cb < CBOOK / NSPLIT; cb += BN) {
        const int cbase = cStart + cb;
#pragma unroll
        for (int i = 0; i < 8; i++)
#pragma unroll
            for (int j = 0; j < 8; j++) acc[i][j] = 0.f;

        for (int kk = 0; kk < DIM; kk += KB) {
            __syncthreads();
            {
                int r  = tid >> 2;
                int k4 = (tid & 3) * 4;
                float4 v = *(const float4*)&x[(rowBase + r) * DIM + kk + k4];
                xs[k4 + 0][r] = v.x; xs[k4 + 1][r] = v.y;
                xs[k4 + 2][r] = v.z; xs[k4 + 3][r] = v.w;
            }
            {
                const float4* src = (const float4*)&embed[(cbase + tid) * DIM + kk];
#pragma unroll
                for (int q = 0; q < 4; q++) {
                    float4 v = src[q];
                    es[q * 4 + 0][tid] = v.x; es[q * 4 + 1][tid] = v.y;
                    es[q * 4 + 2][tid] = v.z; es[q * 4 + 3][tid] = v.w;
                }
            }
            __syncthreads();
#pragma unroll
            for (int k = 0; k < KB; k++) {
                float xr[8], er[8];
                *(float4*)&xr[0] = *(const float4*)&xs[k][ty * 8];
                *(float4*)&xr[4] = *(const float4*)&xs[k][ty * 8 + 4];
                *(float4*)&er[0] = *(const float4*)&es[k][tx * 4];
                *(float4*)&er[4] = *(const float4*)&es[k][128 + tx * 4];
#pragma unroll
                for (int i = 0; i < 8; i++)
#pragma unroll
                    for (int j = 0; j < 8; j++)
                        acc[i][j] = fmaf(xr[i], er[j], acc[i][j]);
            }
        }
#pragma unroll
        for (int j = 0; j < 8; j++) {
            int c = cbase + ((j < 4) ? (tx * 4 + j) : (128 + tx * 4 + (j - 4)));
            float en = enorm[c];
#pragma unroll
            for (int i = 0; i < 8; i++) {
                float s = en - 2.f * acc[i][j];
                if (s < bestS[i]) { bestS[i] = s; bestC[i] = c; }
            }
        }
    }

#pragma unroll
    for (int i = 0; i < 8; i++) {
        unsigned long long key =
            ((unsigned long long)fkey(bestS[i]) << 32) | (unsigned int)bestC[i];
        for (int m = 16; m >= 1; m >>= 1) {
            unsigned long long o = __shfl_xor(key, m, 64);
            if (o < key) key = o;
        }
        if (tx == 0) atomicMin(&keys[rowBase + ty * 8 + i], key);
    }
}

// ---------- scatter: quantize gather, ind write, counts, 0.2*x into avg ----------
__global__ __launch_bounds__(256) void scatter_kernel(const float* __restrict__ x,
                                                      const float* __restrict__ embed,
                                                      const unsigned long long* __restrict__ keys,
                                                      float* __restrict__ quant,
                                                      float* __restrict__ ind_out,
                                                      float* __restrict__ counts,
                                                      float* __restrict__ avg_out) {
    int i = blockIdx.x * 256 + threadIdx.x;
    int row = i >> 6;
    int c4  = (i & 63) * 4;
    int idx = (int)(keys[row] & 0xFFFFFFFFull);
    float4 e = *(const float4*)&embed[idx * DIM + c4];
    *(float4*)&quant[row * DIM + c4] = e;
    float4 xv = *(const float4*)&x[row * DIM + c4];
    atomicAdd(&avg_out[idx * DIM + c4 + 0], OMD_F * xv.x);
    atomicAdd(&avg_out[idx * DIM + c4 + 1], OMD_F * xv.y);
    atomicAdd(&avg_out[idx * DIM + c4 + 2], OMD_F * xv.z);
    atomicAdd(&avg_out[idx * DIM + c4 + 3], OMD_F * xv.w);
    if ((i & 63) == 0) {
        ind_out[row] = (float)idx;
        atomicAdd(&counts[idx], 1.0f);
    }
}

// ---------- cluster_size_new + total sum ----------
__global__ __launch_bounds__(256) void csn_kernel(const float* __restrict__ cluster_size,
                                                  const float* __restrict__ counts,
                                                  float* __restrict__ csn_out,
                                                  float* __restrict__ total) {
    int c = blockIdx.x * 256 + threadIdx.x;
    float v = DECAY_F * cluster_size[c] + OMD_F * counts[c];
    csn_out[c] = v;
    float s = v;
    for (int m = 32; m >= 1; m >>= 1) s += __shfl_xor(s, m, 64);
    __shared__ float ws4[4];
    if ((threadIdx.x & 63) == 0) ws4[threadIdx.x >> 6] = s;
    __syncthreads();
    if (threadIdx.x == 0) atomicAdd(total, ws4[0] + ws4[1] + ws4[2] + ws4[3]);
}

// ---------- embed_normalized = avg_new / cs ----------
__global__ __launch_bounds__(256) void norm_kernel(const float* __restrict__ avg_new,
                                                   const float* __restrict__ csn,
                                                   const float* __restrict__ total,
                                                   float* __restrict__ out) {
    int i = blockIdx.x * 256 + threadIdx.x;
    int c = i >> 6;
    float tot = *total;
    float smoothed = (csn[c] + EPS_F) / (tot + (float)CBOOK * EPS_F);
    float cs = smoothed * tot;
    float4 v = ((const float4*)avg_new)[i];
    v.x = v.x / cs; v.y = v.y / cs; v.z = v.z / cs; v.w = v.w / cs;
    ((float4*)out)[i] = v;
}

extern "C" void kernel_launch(void* const* d_in, const int* in_sizes, int n_in,
                              void* d_out, int out_size, void* d_ws, size_t ws_size,
                              hipStream_t stream) {
    const float* x            = (const float*)d_in[0];
    const float* embed        = (const float*)d_in[1];
    const float* cluster_size = (const float*)d_in[2];
    const float* embed_avg    = (const float*)d_in[3];
    float* out = (float*)d_out;
    char*  ws  = (char*)d_ws;

    unsigned long long* keys = (unsigned long long*)(ws + WS_KEYS);
    float* enorm  = (float*)(ws + WS_ENORM);
    float* counts = (float*)(ws + WS_COUNTS);
    float* total  = (float*)(ws + WS_TOTAL);

    hipMemsetAsync(ws + WS_KEYS, 0xFF, NROWS * 8, stream);
    hipMemsetAsync(ws + WS_COUNTS, 0, CBOOK * 4 + 4, stream);

    if (ws_size >= (size_t)WS_NEED) {
        unsigned short* xsplit = (unsigned short*)(ws + WS_XSPLIT);
        unsigned short* esplit = (unsigned short*)(ws + WS_ESPLIT_OFF);
        prep_kernel<<<6144, 256, 0, stream>>>(x, embed, embed_avg,
                                              xsplit, esplit, enorm, out + O_AVG);
        dim3 grid(CBOOK / 128, NROWS / 128);
        mfma_argmin_kernel<<<grid, 256, 0, stream>>>(xsplit, esplit, enorm, keys);
    } else {
        init_avg_kernel<<<(CBOOK * DIM / 4) / 256, 256, 0, stream>>>(embed_avg, out + O_AVG);
        enorm_kernel<<<CBOOK / 4, 256, 0, stream>>>(embed, enorm);
        dim3 grid(NROWS / BM, NSPLIT);
        argmin_kernel<<<grid, 256, 0, stream>>>(x, embed, enorm, keys);
    }

    scatter_kernel<<<(NROWS * DIM / 4) / 256, 256, 0, stream>>>(
        x, embed, keys, out + O_QUANT, out + O_IND, counts, out + O_AVG);

    csn_kernel<<<CBOOK / 256, 256, 0, stream>>>(cluster_size, counts, out + O_CSN, total);

    norm_kernel<<<(CBOOK * DIM / 4) / 256, 256, 0, stream>>>(
        out + O_AVG, out + O_CSN, total, out + O_NORM);
}